// Round 13
// baseline (1375.252 us; speedup 1.0000x reference)
//
#include <hip/hip_runtime.h>
#include <hip/hip_bf16.h>

#define N_MOL 128
#define STRESS_FLOATS (N_MOL * 9)   // 1152
#define NB 128                      // buckets (power of 2)
#define APB 1563                    // atoms per bucket: 128*1563 = 200064 >= 200000
#define EPB 1024                    // edges per scatter block
#define K_PT 4                      // EPB / BLK
#define BLK 256
#define RS_SLICES 8

// ---------------------------------------------------------------------------
__global__ void zero_f32_kernel(float* __restrict__ p, size_t n) {
    size_t i = (size_t)blockIdx.x * blockDim.x + threadIdx.x;
    if (i < n) p[i] = 0.f;
}

// ---------------------------------------------------------------------------
// Pass C: histogram -> wave0 shfl-scan (1 barrier) -> reservation ->
// LDS bucket-major staging -> coalesced stream-out (~256B runs).
// Stress: LDS accumulate -> spart[blockIdx] += (accumulated across chunks).
// ---------------------------------------------------------------------------
__global__ void __launch_bounds__(256)
scatter_kernel(const float* __restrict__ dEdRij,
               const float* __restrict__ Rij,
               const int*   __restrict__ idx_i,
               const int*   __restrict__ idx_j,
               const int*   __restrict__ idx_m,
               float4* __restrict__ rec,    // [NB][CAP]
               int*    __restrict__ cnt,    // [NB] (this chunk's slice)
               float*  __restrict__ spart,  // [rows][1152], += across chunks
               int e0_chunk, int n_edges_chunk, int CAP)
{
    __shared__ int    hist[NB];
    __shared__ int    excl[NB];
    __shared__ int    cur[NB];
    __shared__ int    shiftb[NB];
    __shared__ float  smem[STRESS_FLOATS];
    __shared__ float4 stg[EPB * 2];    // 32 KB bucket-major staging

    for (int t = threadIdx.x; t < NB; t += blockDim.x) hist[t] = 0;
    for (int t = threadIdx.x; t < STRESS_FLOATS; t += blockDim.x) smem[t] = 0.f;
    __syncthreads();

    const int be0 = e0_chunk + blockIdx.x * EPB;
    const int be1 = min(be0 + EPB, e0_chunk + n_edges_chunk);

    // ---- phase 1: idx loads into regs + LDS histogram
    int ei[K_PT], ej[K_PT];
    #pragma unroll
    for (int k = 0; k < K_PT; ++k) {
        const int e = be0 + k * BLK + threadIdx.x;
        ei[k] = -1; ej[k] = -1;
        if (e < be1) {
            ei[k] = idx_i[e];
            ej[k] = idx_j[e];
            atomicAdd(&hist[ei[k] / APB], 1);
            atomicAdd(&hist[ej[k] / APB], 1);
        }
    }
    __syncthreads();                       // histogram complete

    // ---- wave-0 exclusive scan over NB=128 (2 entries/lane, shfl, no barriers)
    if (threadIdx.x < 64) {
        const int l = threadIdx.x;
        const int a = hist[2 * l], b = hist[2 * l + 1];
        int s = a + b;
        #pragma unroll
        for (int off = 1; off < 64; off <<= 1) {
            const int v = __shfl_up(s, off, 64);
            if (l >= off) s += v;
        }
        const int excl_pair = s - (a + b);   // sum of pairs before this lane
        excl[2 * l]     = excl_pair;
        excl[2 * l + 1] = excl_pair + a;
    }
    __syncthreads();

    // ---- reservation: one global atomic per non-empty bucket
    for (int t = threadIdx.x; t < NB; t += blockDim.x) {
        const int h  = hist[t];
        const int ex = excl[t];
        const int g  = h ? atomicAdd(&cnt[t], h) : 0;
        cur[t]    = ex;                   // staging cursor
        shiftb[t] = t * CAP + g - ex;     // rec idx = stg idx + shift
    }
    __syncthreads();

    // ---- phase 2: float loads, stress accum, bucket-major staging
    #pragma unroll
    for (int k = 0; k < K_PT; ++k) {
        const int e = be0 + k * BLK + threadIdx.x;
        if (e >= be1) continue;
        const int i = ei[k], j = ej[k];
        const float dx = dEdRij[3*e+0], dy = dEdRij[3*e+1], dz = dEdRij[3*e+2];
        const float rx = Rij[3*e+0],    ry = Rij[3*e+1],    rz = Rij[3*e+2];

        const int m = idx_m[i];
        float* s = &smem[m * 9];
        atomicAdd(&s[0], rx * dx);
        atomicAdd(&s[1], rx * dy);
        atomicAdd(&s[2], rx * dz);
        atomicAdd(&s[3], ry * dx);
        atomicAdd(&s[4], ry * dy);
        atomicAdd(&s[5], ry * dz);
        atomicAdd(&s[6], rz * dx);
        atomicAdd(&s[7], rz * dy);
        atomicAdd(&s[8], rz * dz);

        int p = atomicAdd(&cur[i / APB], 1);
        stg[p] = make_float4(__int_as_float(i), dx, dy, dz);
        p = atomicAdd(&cur[j / APB], 1);
        stg[p] = make_float4(__int_as_float(j), -dx, -dy, -dz);
    }
    __syncthreads();

    // ---- stream-out: ~16-record (256 B) runs per bucket -> coalesced
    const int total = 2 * (be1 - be0);
    for (int t = threadIdx.x; t < total; t += blockDim.x) {
        const float4 q = stg[t];
        const int a = __float_as_int(q.x);
        const int b = a / APB;
        const int gidx = t + shiftb[b];
        if (gidx < (b + 1) * CAP)         // capacity guard (drop-only)
            rec[gidx] = q;
    }

    __syncthreads();
    float* sp = spart + (size_t)blockIdx.x * STRESS_FLOATS;
    for (int t = threadIdx.x; t < STRESS_FLOATS; t += blockDim.x)
        sp[t] += smem[t];
}

// ---------------------------------------------------------------------------
// Pass D: one block per bucket; 4-way unrolled loads -> LDS accumulate ->
// non-atomic += into forces (exclusive atom ownership per block).
// ---------------------------------------------------------------------------
__global__ void __launch_bounds__(256)
accum_kernel(const float4* __restrict__ rec,
             const int*    __restrict__ cnt,
             float* __restrict__ forces,
             int CAP, int n3)
{
    __shared__ float facc[APB * 3];      // 18.8 KB
    const int b = blockIdx.x;
    for (int t = threadIdx.x; t < APB * 3; t += blockDim.x) facc[t] = 0.f;
    __syncthreads();

    int n = cnt[b];
    if (n > CAP) n = CAP;
    const float4* rb = rec + (size_t)b * CAP;
    const int abase = b * APB;

#define ACC(q)                                             \
    {                                                      \
        const int l = __float_as_int((q).x) - abase;       \
        atomicAdd(&facc[l * 3 + 0], (q).y);                \
        atomicAdd(&facc[l * 3 + 1], (q).z);                \
        atomicAdd(&facc[l * 3 + 2], (q).w);                \
    }

    int r = threadIdx.x;
    for (; r + 3 * BLK < n; r += 4 * BLK) {
        const float4 q0 = rb[r];
        const float4 q1 = rb[r + BLK];
        const float4 q2 = rb[r + 2 * BLK];
        const float4 q3 = rb[r + 3 * BLK];
        ACC(q0); ACC(q1); ACC(q2); ACC(q3);
    }
    for (; r < n; r += BLK) {
        const float4 q = rb[r];
        ACC(q);
    }
#undef ACC

    __syncthreads();
    const int o = abase * 3;
    for (int t = threadIdx.x; t < APB * 3; t += blockDim.x) {
        const int a3 = o + t;
        if (a3 < n3) forces[a3] += facc[t];
    }
}

// ---------------------------------------------------------------------------
// Stress reduce, 2-stage (rows ~2000; avoid r9's serial single-block walk).
// stage1: slice s sums rows s, s+8, ... -> stmp[s][1152] (coalesced, 9216 thr)
// stage2: 1152 threads sum 8 slices, divide by cell volume.
// ---------------------------------------------------------------------------
__global__ void reduce_stress_stage1(const float* __restrict__ spart,
                                     float* __restrict__ stmp, int rows)
{
    const int t = blockIdx.x * blockDim.x + threadIdx.x;
    if (t >= STRESS_FLOATS * RS_SLICES) return;
    const int col = t % STRESS_FLOATS;
    const int sl  = t / STRESS_FLOATS;
    float acc = 0.f;
    for (int r = sl; r < rows; r += RS_SLICES)
        acc += spart[(size_t)r * STRESS_FLOATS + col];
    stmp[sl * STRESS_FLOATS + col] = acc;
}

__global__ void reduce_stress_stage2(const float* __restrict__ stmp,
                                     const float* __restrict__ cell,
                                     float* __restrict__ out_stress)
{
    const int t = blockIdx.x * blockDim.x + threadIdx.x;
    if (t >= STRESS_FLOATS) return;
    float acc = 0.f;
    #pragma unroll
    for (int s = 0; s < RS_SLICES; ++s)
        acc += stmp[s * STRESS_FLOATS + t];
    const int m = t / 9;
    const float* c = &cell[m * 9];
    const float a0 = c[0], a1 = c[1], a2 = c[2];
    const float b0 = c[3], b1 = c[4], b2 = c[5];
    const float c0 = c[6], c1 = c[7], c2 = c[8];
    const float x0 = b1 * c2 - b2 * c1;
    const float x1 = b2 * c0 - b0 * c2;
    const float x2 = b0 * c1 - b1 * c0;
    const float vol = a0 * x0 + a1 * x1 + a2 * x2;
    out_stress[t] = acc / vol;
}

// ===========================================================================
// Fallback: round-6 measured f64 atomic path (known passing)
// ===========================================================================
__global__ void zero_f64_kernel(double* __restrict__ p, int n) {
    int i = blockIdx.x * blockDim.x + threadIdx.x;
    if (i < n) p[i] = 0.0;
}

__global__ void __launch_bounds__(256)
edge_kernel_f64(const float* __restrict__ dEdRij,
                const float* __restrict__ Rij,
                const int*   __restrict__ idx_i,
                const int*   __restrict__ idx_j,
                const int*   __restrict__ idx_m,
                double* __restrict__ facc,
                float*  __restrict__ spart,
                int E)
{
    __shared__ float smem[STRESS_FLOATS];
    for (int t = threadIdx.x; t < STRESS_FLOATS; t += blockDim.x) smem[t] = 0.f;
    __syncthreads();
    const int stride = gridDim.x * blockDim.x;
    for (int e = blockIdx.x * blockDim.x + threadIdx.x; e < E; e += stride) {
        const int i = idx_i[e], j = idx_j[e];
        const float dx = dEdRij[3*e+0], dy = dEdRij[3*e+1], dz = dEdRij[3*e+2];
        const float rx = Rij[3*e+0],    ry = Rij[3*e+1],    rz = Rij[3*e+2];
        double* fi = facc + 3 * (size_t)i;
        unsafeAtomicAdd(fi + 0, (double) dx);
        unsafeAtomicAdd(fi + 1, (double) dy);
        unsafeAtomicAdd(fi + 2, (double) dz);
        double* fj = facc + 3 * (size_t)j;
        unsafeAtomicAdd(fj + 0, (double)-dx);
        unsafeAtomicAdd(fj + 1, (double)-dy);
        unsafeAtomicAdd(fj + 2, (double)-dz);
        const int m = idx_m[i];
        float* s = &smem[m * 9];
        atomicAdd(&s[0], rx*dx); atomicAdd(&s[1], rx*dy); atomicAdd(&s[2], rx*dz);
        atomicAdd(&s[3], ry*dx); atomicAdd(&s[4], ry*dy); atomicAdd(&s[5], ry*dz);
        atomicAdd(&s[6], rz*dx); atomicAdd(&s[7], rz*dy); atomicAdd(&s[8], rz*dz);
    }
    __syncthreads();
    float* sp = spart + (size_t)blockIdx.x * STRESS_FLOATS;
    for (int t = threadIdx.x; t < STRESS_FLOATS; t += blockDim.x) sp[t] = smem[t];
}

__global__ void reduce_forces_f64_kernel(const double* __restrict__ facc,
                                         float* __restrict__ forces, int n3)
{
    int t = blockIdx.x * blockDim.x + threadIdx.x;
    if (t < n3) forces[t] = (float)facc[t];
}

__global__ void reduce_stress_rows_kernel(const float* __restrict__ spart,
                                          const float* __restrict__ cell,
                                          float* __restrict__ out_stress,
                                          int rows)
{
    int t = blockIdx.x * blockDim.x + threadIdx.x;
    if (t >= STRESS_FLOATS) return;
    float acc = 0.f;
    for (int b = 0; b < rows; ++b)
        acc += spart[(size_t)b * STRESS_FLOATS + t];
    const int m = t / 9;
    const float* c = &cell[m * 9];
    const float a0 = c[0], a1 = c[1], a2 = c[2];
    const float b0 = c[3], b1 = c[4], b2 = c[5];
    const float c0 = c[6], c1 = c[7], c2 = c[8];
    const float x0 = b1*c2 - b2*c1, x1 = b2*c0 - b0*c2, x2 = b0*c1 - b1*c0;
    const float vol = a0*x0 + a1*x1 + a2*x2;
    out_stress[t] = acc / vol;
}

// ===========================================================================
extern "C" void kernel_launch(void* const* d_in, const int* in_sizes, int n_in,
                              void* d_out, int out_size, void* d_ws, size_t ws_size,
                              hipStream_t stream)
{
    const float* dEdRij = (const float*)d_in[0];
    const float* Rij    = (const float*)d_in[1];
    const float* R      = (const float*)d_in[2];  (void)R;
    const float* cell   = (const float*)d_in[3];
    const int*   idx_i  = (const int*)d_in[4];
    const int*   idx_j  = (const int*)d_in[5];
    const int*   idx_m  = (const int*)d_in[6];

    const int E  = in_sizes[0] / 3;   // 10,000,000
    const int N  = in_sizes[2] / 3;   // 200,000
    const int n3 = N * 3;

    float* out        = (float*)d_out;
    float* forces     = out;
    float* stress_out = out + (size_t)n3;

    // ---- choose fewest chunks that fit:
    //      rec[NB][CAP] + spart[rows][1152] + cnt[nchunks][NB] + stmp
    int nchunks = 0, CAP = 0, ROWS = 0;
    size_t rec_f4 = 0, spart_f = 0;
    {
        const int cand[10] = {4, 5, 6, 8, 10, 12, 16, 20, 25, 40};
        for (int ci = 0; ci < 10; ++ci) {
            int nc   = cand[ci];
            int CH   = (E + nc - 1) / nc;
            int cap  = (3 * CH) / NB + 64;       // 1.5x mean headroom
            int rows = (CH + EPB - 1) / EPB;
            size_t need = (size_t)NB * cap * sizeof(float4)
                        + (size_t)rows * STRESS_FLOATS * sizeof(float)
                        + (size_t)nc * NB * sizeof(int)
                        + (size_t)RS_SLICES * STRESS_FLOATS * sizeof(float)
                        + 256;
            if (need <= ws_size) {
                nchunks = nc; CAP = cap; ROWS = rows;
                rec_f4  = (size_t)NB * cap;
                spart_f = (size_t)rows * STRESS_FLOATS;
                break;
            }
        }
    }

    if (nchunks > 0) {
        float4* rec   = (float4*)d_ws;
        float*  spart = (float*)(rec + rec_f4);
        int*    cnt   = (int*)(spart + spart_f);            // [nchunks][NB]
        float*  stmp  = (float*)(cnt + (size_t)nchunks * NB); // [8][1152]

        // zero spart + cnt slices (contiguous 4B words)
        const size_t zf = spart_f + (size_t)nchunks * NB;
        zero_f32_kernel<<<(int)((zf + BLK - 1) / BLK), BLK, 0, stream>>>(
            spart, zf);
        zero_f32_kernel<<<(n3 + BLK - 1) / BLK, BLK, 0, stream>>>(
            forces, (size_t)n3);

        const int CH = (E + nchunks - 1) / nchunks;
        int chunk = 0;
        for (int s = 0; s < E; s += CH, ++chunk) {
            const int ce = min(CH, E - s);
            const int nb = (ce + EPB - 1) / EPB;

            scatter_kernel<<<nb, BLK, 0, stream>>>(
                dEdRij, Rij, idx_i, idx_j, idx_m,
                rec, cnt + (size_t)chunk * NB, spart, s, ce, CAP);

            accum_kernel<<<NB, BLK, 0, stream>>>(
                rec, cnt + (size_t)chunk * NB, forces, CAP, n3);
        }

        reduce_stress_stage1<<<(STRESS_FLOATS * RS_SLICES + BLK - 1) / BLK,
                               BLK, 0, stream>>>(spart, stmp, ROWS);
        reduce_stress_stage2<<<(STRESS_FLOATS + BLK - 1) / BLK, BLK, 0, stream>>>(
            stmp, cell, stress_out);
    } else {
        // fallback: measured f64 atomic path
        double* facc   = (double*)d_ws;
        float*  spartf = (float*)(facc + n3);

        zero_f64_kernel<<<(n3 + BLK - 1) / BLK, BLK, 0, stream>>>(facc, n3);
        edge_kernel_f64<<<2048, BLK, 0, stream>>>(
            dEdRij, Rij, idx_i, idx_j, idx_m, facc, spartf, E);
        reduce_forces_f64_kernel<<<(n3 + BLK - 1) / BLK, BLK, 0, stream>>>(
            facc, forces, n3);
        reduce_stress_rows_kernel<<<(STRESS_FLOATS + BLK - 1) / BLK, BLK, 0, stream>>>(
            spartf, cell, stress_out, 2048);
    }
}

// Round 14
// 1001.269 us; speedup vs baseline: 1.3735x; 1.3735x over previous
//
#include <hip/hip_runtime.h>
#include <hip/hip_bf16.h>
#include <hip/hip_fp16.h>

#define N_MOL 128
#define STRESS_FLOATS (N_MOL * 9)   // 1152
#define NB 128                      // buckets
#define APB 1563                    // atoms/bucket: 128*1563 = 200064 >= 200000
#define NPAD (NB * APB)             // padded atom count
#define EPB 1024                    // edges per scatter block
#define K_PT 4                      // EPB / BLK
#define BLK 256
#define RS_SLICES 16

// ---------------------------------------------------------------------------
__global__ void zero_f32_kernel(float* __restrict__ p, size_t n) {
    size_t i = (size_t)blockIdx.x * blockDim.x + threadIdx.x;
    if (i < n) p[i] = 0.f;
}

__device__ __forceinline__ unsigned short h16(float v) {
    return __half_as_ushort(__float2half_rn(v));
}

// ---------------------------------------------------------------------------
// Pass C: histogram -> wave0 shfl scan -> reservation -> bucket-major LDS
// staging of 8-byte records -> coalesced stream-out (~128B runs).
// Record: word0 = (local_id<<16) | f16(fx); word1 = f16(fy) | f16(fz)<<16.
// Stress: LDS accumulate -> spart[blockIdx] += (across chunks).
// ---------------------------------------------------------------------------
__global__ void __launch_bounds__(256)
scatter_kernel(const float* __restrict__ dEdRij,
               const float* __restrict__ Rij,
               const int*   __restrict__ idx_i,
               const int*   __restrict__ idx_j,
               const int*   __restrict__ idx_m,
               uint2* __restrict__ rec,     // [NB][CAP]
               int*   __restrict__ cnt,     // [NB] (this chunk's slice)
               float* __restrict__ spart,   // [rows][1152], += across chunks
               int e0_chunk, int n_edges_chunk, int CAP)
{
    __shared__ int           hist[NB];
    __shared__ int           excl[NB];
    __shared__ int           cur[NB];
    __shared__ int           shiftb[NB];
    __shared__ float         smem[STRESS_FLOATS];
    __shared__ uint2         stg[EPB * 2];      // 16 KB
    __shared__ unsigned char stgb[EPB * 2];     // bucket of each staged rec, 2 KB

    for (int t = threadIdx.x; t < NB; t += blockDim.x) hist[t] = 0;
    for (int t = threadIdx.x; t < STRESS_FLOATS; t += blockDim.x) smem[t] = 0.f;
    __syncthreads();

    const int be0 = e0_chunk + blockIdx.x * EPB;
    const int be1 = min(be0 + EPB, e0_chunk + n_edges_chunk);

    // ---- phase 1: idx loads into regs + LDS histogram
    int ei[K_PT], ej[K_PT];
    #pragma unroll
    for (int k = 0; k < K_PT; ++k) {
        const int e = be0 + k * BLK + threadIdx.x;
        ei[k] = -1; ej[k] = -1;
        if (e < be1) {
            ei[k] = idx_i[e];
            ej[k] = idx_j[e];
            atomicAdd(&hist[ei[k] / APB], 1);
            atomicAdd(&hist[ej[k] / APB], 1);
        }
    }
    __syncthreads();                       // histogram complete (r11 lesson)

    // ---- wave-0 exclusive scan over NB=128 (2 entries/lane, shfl)
    if (threadIdx.x < 64) {
        const int l = threadIdx.x;
        const int a = hist[2 * l], b = hist[2 * l + 1];
        int s = a + b;
        #pragma unroll
        for (int off = 1; off < 64; off <<= 1) {
            const int v = __shfl_up(s, off, 64);
            if (l >= off) s += v;
        }
        const int excl_pair = s - (a + b);
        excl[2 * l]     = excl_pair;
        excl[2 * l + 1] = excl_pair + a;
    }
    __syncthreads();

    // ---- reservation: one global atomic per non-empty bucket
    for (int t = threadIdx.x; t < NB; t += blockDim.x) {
        const int h  = hist[t];
        const int ex = excl[t];
        const int g  = h ? atomicAdd(&cnt[t], h) : 0;
        cur[t]    = ex;
        shiftb[t] = t * CAP + g - ex;     // rec idx = stg idx + shift
    }
    __syncthreads();

    // ---- phase 2: float loads, stress accum, 8B bucket-major staging
    #pragma unroll
    for (int k = 0; k < K_PT; ++k) {
        const int e = be0 + k * BLK + threadIdx.x;
        if (e >= be1) continue;
        const int i = ei[k], j = ej[k];
        const float dx = dEdRij[3*e+0], dy = dEdRij[3*e+1], dz = dEdRij[3*e+2];
        const float rx = Rij[3*e+0],    ry = Rij[3*e+1],    rz = Rij[3*e+2];

        const int m = idx_m[i];
        float* s = &smem[m * 9];
        atomicAdd(&s[0], rx * dx);
        atomicAdd(&s[1], rx * dy);
        atomicAdd(&s[2], rx * dz);
        atomicAdd(&s[3], ry * dx);
        atomicAdd(&s[4], ry * dy);
        atomicAdd(&s[5], ry * dz);
        atomicAdd(&s[6], rz * dx);
        atomicAdd(&s[7], rz * dy);
        atomicAdd(&s[8], rz * dz);

        // i-record
        const int bi = i / APB;
        const int li = i - bi * APB;
        uint2 q;
        q.x = ((unsigned)li << 16) | h16(dx);
        q.y = (unsigned)h16(dy) | ((unsigned)h16(dz) << 16);
        int p = atomicAdd(&cur[bi], 1);
        stg[p] = q; stgb[p] = (unsigned char)bi;

        // j-record (negated)
        const int bj = j / APB;
        const int lj = j - bj * APB;
        q.x = ((unsigned)lj << 16) | h16(-dx);
        q.y = (unsigned)h16(-dy) | ((unsigned)h16(-dz) << 16);
        p = atomicAdd(&cur[bj], 1);
        stg[p] = q; stgb[p] = (unsigned char)bj;
    }
    __syncthreads();

    // ---- stream-out: ~16-record (128 B) runs per bucket -> coalesced
    const int total = 2 * (be1 - be0);
    for (int t = threadIdx.x; t < total; t += blockDim.x) {
        const int b = stgb[t];
        const int gidx = t + shiftb[b];
        if (gidx < (b + 1) * CAP)          // capacity guard (drop-only)
            rec[gidx] = stg[t];
    }

    __syncthreads();
    float* sp = spart + (size_t)blockIdx.x * STRESS_FLOATS;
    for (int t = threadIdx.x; t < STRESS_FLOATS; t += blockDim.x)
        sp[t] += smem[t];
}

// ---------------------------------------------------------------------------
// Pass D: TWO blocks per bucket (full-GPU grid of 256). Block (b,s) reads
// segment s of bucket b's records, accumulates in LDS, then += into its own
// partial array (exclusive per (s,b), accumulated across chunks).
// ---------------------------------------------------------------------------
__global__ void __launch_bounds__(256)
accum_kernel(const uint2* __restrict__ rec,
             const int*   __restrict__ cnt,
             float* __restrict__ partial,   // [2][NPAD*3]
             int CAP)
{
    __shared__ float facc[APB * 3];        // 18.8 KB
    const int b = blockIdx.x >> 1;
    const int s = blockIdx.x & 1;
    for (int t = threadIdx.x; t < APB * 3; t += blockDim.x) facc[t] = 0.f;
    __syncthreads();

    int n = cnt[b];
    if (n > CAP) n = CAP;
    const int r0 = s ? (n >> 1) : 0;
    const int r1 = s ? n : (n >> 1);
    const uint2* rb = rec + (size_t)b * CAP;

#define ACC(q)                                                        \
    {                                                                 \
        const int   l  = (int)((q).x >> 16);                          \
        const float fx = __half2float(__ushort_as_half(               \
                             (unsigned short)((q).x & 0xffffu)));     \
        const float fy = __half2float(__ushort_as_half(               \
                             (unsigned short)((q).y & 0xffffu)));     \
        const float fz = __half2float(__ushort_as_half(               \
                             (unsigned short)((q).y >> 16)));         \
        atomicAdd(&facc[l * 3 + 0], fx);                              \
        atomicAdd(&facc[l * 3 + 1], fy);                              \
        atomicAdd(&facc[l * 3 + 2], fz);                              \
    }

    int r = r0 + threadIdx.x;
    for (; r + BLK < r1; r += 2 * BLK) {
        const uint2 q0 = rb[r];
        const uint2 q1 = rb[r + BLK];
        ACC(q0); ACC(q1);
    }
    for (; r < r1; r += BLK) {
        const uint2 q = rb[r];
        ACC(q);
    }
#undef ACC

    __syncthreads();
    float* pp = partial + ((size_t)s * NPAD + (size_t)b * APB) * 3;
    for (int t = threadIdx.x; t < APB * 3; t += blockDim.x)
        pp[t] += facc[t];
}

// ---------------------------------------------------------------------------
// forces = p0 + p1 (full overwrite of d_out forces region)
// ---------------------------------------------------------------------------
__global__ void final_forces_kernel(const float* __restrict__ partial,
                                    float* __restrict__ forces, int n3)
{
    const int t = blockIdx.x * blockDim.x + threadIdx.x;
    if (t < n3) forces[t] = partial[t] + partial[(size_t)NPAD * 3 + t];
}

// ---------------------------------------------------------------------------
// Stress reduce, 2-stage
// ---------------------------------------------------------------------------
__global__ void reduce_stress_stage1(const float* __restrict__ spart,
                                     float* __restrict__ stmp, int rows)
{
    const int t = blockIdx.x * blockDim.x + threadIdx.x;
    if (t >= STRESS_FLOATS * RS_SLICES) return;
    const int col = t % STRESS_FLOATS;
    const int sl  = t / STRESS_FLOATS;
    float acc = 0.f;
    for (int r = sl; r < rows; r += RS_SLICES)
        acc += spart[(size_t)r * STRESS_FLOATS + col];
    stmp[sl * STRESS_FLOATS + col] = acc;
}

__global__ void reduce_stress_stage2(const float* __restrict__ stmp,
                                     const float* __restrict__ cell,
                                     float* __restrict__ out_stress)
{
    const int t = blockIdx.x * blockDim.x + threadIdx.x;
    if (t >= STRESS_FLOATS) return;
    float acc = 0.f;
    #pragma unroll
    for (int s = 0; s < RS_SLICES; ++s)
        acc += stmp[s * STRESS_FLOATS + t];
    const int m = t / 9;
    const float* c = &cell[m * 9];
    const float a0 = c[0], a1 = c[1], a2 = c[2];
    const float b0 = c[3], b1 = c[4], b2 = c[5];
    const float c0 = c[6], c1 = c[7], c2 = c[8];
    const float x0 = b1 * c2 - b2 * c1;
    const float x1 = b2 * c0 - b0 * c2;
    const float x2 = b0 * c1 - b1 * c0;
    const float vol = a0 * x0 + a1 * x1 + a2 * x2;
    out_stress[t] = acc / vol;
}

// ===========================================================================
// Fallback: round-6 measured f64 atomic path (known passing)
// ===========================================================================
__global__ void zero_f64_kernel(double* __restrict__ p, int n) {
    int i = blockIdx.x * blockDim.x + threadIdx.x;
    if (i < n) p[i] = 0.0;
}

__global__ void __launch_bounds__(256)
edge_kernel_f64(const float* __restrict__ dEdRij,
                const float* __restrict__ Rij,
                const int*   __restrict__ idx_i,
                const int*   __restrict__ idx_j,
                const int*   __restrict__ idx_m,
                double* __restrict__ facc,
                float*  __restrict__ spart,
                int E)
{
    __shared__ float smem[STRESS_FLOATS];
    for (int t = threadIdx.x; t < STRESS_FLOATS; t += blockDim.x) smem[t] = 0.f;
    __syncthreads();
    const int stride = gridDim.x * blockDim.x;
    for (int e = blockIdx.x * blockDim.x + threadIdx.x; e < E; e += stride) {
        const int i = idx_i[e], j = idx_j[e];
        const float dx = dEdRij[3*e+0], dy = dEdRij[3*e+1], dz = dEdRij[3*e+2];
        const float rx = Rij[3*e+0],    ry = Rij[3*e+1],    rz = Rij[3*e+2];
        double* fi = facc + 3 * (size_t)i;
        unsafeAtomicAdd(fi + 0, (double) dx);
        unsafeAtomicAdd(fi + 1, (double) dy);
        unsafeAtomicAdd(fi + 2, (double) dz);
        double* fj = facc + 3 * (size_t)j;
        unsafeAtomicAdd(fj + 0, (double)-dx);
        unsafeAtomicAdd(fj + 1, (double)-dy);
        unsafeAtomicAdd(fj + 2, (double)-dz);
        const int m = idx_m[i];
        float* s = &smem[m * 9];
        atomicAdd(&s[0], rx*dx); atomicAdd(&s[1], rx*dy); atomicAdd(&s[2], rx*dz);
        atomicAdd(&s[3], ry*dx); atomicAdd(&s[4], ry*dy); atomicAdd(&s[5], ry*dz);
        atomicAdd(&s[6], rz*dx); atomicAdd(&s[7], rz*dy); atomicAdd(&s[8], rz*dz);
    }
    __syncthreads();
    float* sp = spart + (size_t)blockIdx.x * STRESS_FLOATS;
    for (int t = threadIdx.x; t < STRESS_FLOATS; t += blockDim.x) sp[t] = smem[t];
}

__global__ void reduce_forces_f64_kernel(const double* __restrict__ facc,
                                         float* __restrict__ forces, int n3)
{
    int t = blockIdx.x * blockDim.x + threadIdx.x;
    if (t < n3) forces[t] = (float)facc[t];
}

__global__ void reduce_stress_rows_kernel(const float* __restrict__ spart,
                                          const float* __restrict__ cell,
                                          float* __restrict__ out_stress,
                                          int rows)
{
    int t = blockIdx.x * blockDim.x + threadIdx.x;
    if (t >= STRESS_FLOATS) return;
    float acc = 0.f;
    for (int b = 0; b < rows; ++b)
        acc += spart[(size_t)b * STRESS_FLOATS + t];
    const int m = t / 9;
    const float* c = &cell[m * 9];
    const float a0 = c[0], a1 = c[1], a2 = c[2];
    const float b0 = c[3], b1 = c[4], b2 = c[5];
    const float c0 = c[6], c1 = c[7], c2 = c[8];
    const float x0 = b1*c2 - b2*c1, x1 = b2*c0 - b0*c2, x2 = b0*c1 - b1*c0;
    const float vol = a0*x0 + a1*x1 + a2*x2;
    out_stress[t] = acc / vol;
}

// ===========================================================================
extern "C" void kernel_launch(void* const* d_in, const int* in_sizes, int n_in,
                              void* d_out, int out_size, void* d_ws, size_t ws_size,
                              hipStream_t stream)
{
    const float* dEdRij = (const float*)d_in[0];
    const float* Rij    = (const float*)d_in[1];
    const float* R      = (const float*)d_in[2];  (void)R;
    const float* cell   = (const float*)d_in[3];
    const int*   idx_i  = (const int*)d_in[4];
    const int*   idx_j  = (const int*)d_in[5];
    const int*   idx_m  = (const int*)d_in[6];

    const int E  = in_sizes[0] / 3;   // 10,000,000
    const int N  = in_sizes[2] / 3;   // 200,000
    const int n3 = N * 3;

    float* out        = (float*)d_out;
    float* forces     = out;
    float* stress_out = out + (size_t)n3;

    // ---- choose fewest chunks that fit:
    //  rec[NB][CAP]*8B + spart[rows]*4608B + cnt[nc][NB] + stmp + partial 4.8MB
    int nchunks = 0, CAP = 0, ROWS = 0;
    size_t rec_u2 = 0, spart_f = 0;
    {
        const int cand[10] = {2, 3, 4, 5, 6, 8, 10, 16, 20, 40};
        for (int ci = 0; ci < 10; ++ci) {
            const int nc  = cand[ci];
            const int CH  = (E + nc - 1) / nc;
            const long long mean = 2LL * CH / NB;
            const int cap = (int)(mean + mean / 4 + 64);   // 1.25x headroom
            const int rows = (CH + EPB - 1) / EPB;
            const size_t need = (size_t)NB * cap * sizeof(uint2)
                              + (size_t)rows * STRESS_FLOATS * sizeof(float)
                              + (size_t)nc * NB * sizeof(int)
                              + (size_t)RS_SLICES * STRESS_FLOATS * sizeof(float)
                              + (size_t)2 * NPAD * 3 * sizeof(float)
                              + 256;
            if (need <= ws_size) {
                nchunks = nc; CAP = cap; ROWS = rows;
                rec_u2  = (size_t)NB * cap;
                spart_f = (size_t)rows * STRESS_FLOATS;
                break;
            }
        }
    }

    if (nchunks > 0) {
        uint2* rec   = (uint2*)d_ws;
        float* spart = (float*)(rec + rec_u2);
        int*   cnt   = (int*)(spart + spart_f);               // [nc][NB]
        float* stmp  = (float*)(cnt + (size_t)nchunks * NB);  // [16][1152]
        float* part  = stmp + (size_t)RS_SLICES * STRESS_FLOATS; // [2][NPAD*3]

        // zero spart + cnt + stmp + partials in one contiguous launch
        const size_t zf = spart_f + (size_t)nchunks * NB
                        + (size_t)RS_SLICES * STRESS_FLOATS
                        + (size_t)2 * NPAD * 3;
        zero_f32_kernel<<<(int)((zf + BLK - 1) / BLK), BLK, 0, stream>>>(
            spart, zf);

        const int CH = (E + nchunks - 1) / nchunks;
        int chunk = 0;
        for (int s = 0; s < E; s += CH, ++chunk) {
            const int ce = min(CH, E - s);
            const int nb = (ce + EPB - 1) / EPB;

            scatter_kernel<<<nb, BLK, 0, stream>>>(
                dEdRij, Rij, idx_i, idx_j, idx_m,
                rec, cnt + (size_t)chunk * NB, spart, s, ce, CAP);

            accum_kernel<<<NB * 2, BLK, 0, stream>>>(
                rec, cnt + (size_t)chunk * NB, part, CAP);
        }

        final_forces_kernel<<<(n3 + BLK - 1) / BLK, BLK, 0, stream>>>(
            part, forces, n3);
        reduce_stress_stage1<<<(STRESS_FLOATS * RS_SLICES + BLK - 1) / BLK,
                               BLK, 0, stream>>>(spart, stmp, ROWS);
        reduce_stress_stage2<<<(STRESS_FLOATS + BLK - 1) / BLK, BLK, 0, stream>>>(
            stmp, cell, stress_out);
    } else {
        // fallback: measured f64 atomic path
        double* facc   = (double*)d_ws;
        float*  spartf = (float*)(facc + n3);

        zero_f64_kernel<<<(n3 + BLK - 1) / BLK, BLK, 0, stream>>>(facc, n3);
        edge_kernel_f64<<<2048, BLK, 0, stream>>>(
            dEdRij, Rij, idx_i, idx_j, idx_m, facc, spartf, E);
        reduce_forces_f64_kernel<<<(n3 + BLK - 1) / BLK, BLK, 0, stream>>>(
            facc, forces, n3);
        reduce_stress_rows_kernel<<<(STRESS_FLOATS + BLK - 1) / BLK, BLK, 0, stream>>>(
            spartf, cell, stress_out, 2048);
    }
}